// Round 1
// baseline (1323.693 us; speedup 1.0000x reference)
//
#include <hip/hip_runtime.h>
#include <math.h>

// Problem constants (fixed by the reference)
#define BB    4
#define TT    1024
#define EE    1024
#define HH    16
#define HDIM  64
#define KVMULT 2
#define SS    (TT * KVMULT)     // 2048
#define SCALEQ 0.125f           // HD^-0.5
#define MROWS (BB * TT)         // 4096

// ---------------------------------------------------------------------------
// GEMM: C = alpha * (A @ W^T + bias)
//   A [M,K] row-major, W [N,K] row-major, bias [N]
//   LAYOUT 0: C[m*N + n]  (plain)
//   LAYOUT 1: KV head layout: n -> (mm = n>>10, h = (n>>6)&15, d = n&63),
//             m -> (b = m>>10, t = m&1023), s = 2t+mm,
//             C[((b*HH + h)*SS + s)*HDIM + d]
// Tile: 128(M) x 64(N), BK=32, 256 threads, 8x4 micro-tile.
// ---------------------------------------------------------------------------
template <int LAYOUT>
__global__ __launch_bounds__(256) void gemm_bias_kernel(
    const float* __restrict__ A, const float* __restrict__ W,
    const float* __restrict__ bias, float* __restrict__ C,
    int M, int N, int K, float alpha)
{
    __shared__ __align__(16) float As[32][132];  // [k][m], +4 pad
    __shared__ __align__(16) float Bs[32][68];   // [k][n], +4 pad

    const int tid = threadIdx.x;
    const int tx = tid & 15;   // 0..15 -> n
    const int ty = tid >> 4;   // 0..15 -> m
    const int m0 = blockIdx.x * 128;
    const int n0 = blockIdx.y * 64;

    float acc[8][4];
#pragma unroll
    for (int i = 0; i < 8; ++i)
#pragma unroll
        for (int j = 0; j < 4; ++j) acc[i][j] = 0.0f;

    for (int k0 = 0; k0 < K; k0 += 32) {
        float4 a[4], b[2];
#pragma unroll
        for (int it = 0; it < 4; ++it) {
            int idx = tid + it * 256;          // 0..1023
            int r = idx >> 3;                  // 0..127
            int c = (idx & 7) << 2;            // 0..28
            a[it] = *(const float4*)(A + (size_t)(m0 + r) * K + k0 + c);
        }
#pragma unroll
        for (int it = 0; it < 2; ++it) {
            int idx = tid + it * 256;          // 0..511
            int r = idx >> 3;                  // 0..63
            int c = (idx & 7) << 2;
            b[it] = *(const float4*)(W + (size_t)(n0 + r) * K + k0 + c);
        }
        __syncthreads();
#pragma unroll
        for (int it = 0; it < 4; ++it) {
            int idx = tid + it * 256;
            int r = idx >> 3;
            int c = (idx & 7) << 2;
            As[c + 0][r] = a[it].x; As[c + 1][r] = a[it].y;
            As[c + 2][r] = a[it].z; As[c + 3][r] = a[it].w;
        }
#pragma unroll
        for (int it = 0; it < 2; ++it) {
            int idx = tid + it * 256;
            int r = idx >> 3;
            int c = (idx & 7) << 2;
            Bs[c + 0][r] = b[it].x; Bs[c + 1][r] = b[it].y;
            Bs[c + 2][r] = b[it].z; Bs[c + 3][r] = b[it].w;
        }
        __syncthreads();
#pragma unroll
        for (int k = 0; k < 32; ++k) {
            float av[8], bv[4];
            *(float4*)&av[0] = *(const float4*)&As[k][ty * 8];
            *(float4*)&av[4] = *(const float4*)&As[k][ty * 8 + 4];
            *(float4*)&bv[0] = *(const float4*)&Bs[k][tx * 4];
#pragma unroll
            for (int i = 0; i < 8; ++i)
#pragma unroll
                for (int j = 0; j < 4; ++j)
                    acc[i][j] = fmaf(av[i], bv[j], acc[i][j]);
        }
    }

    const int n = n0 + tx * 4;
    float bvv[4];
    *(float4*)bvv = *(const float4*)(bias + n);

    if (LAYOUT == 0) {
#pragma unroll
        for (int i = 0; i < 8; ++i) {
            int m = m0 + ty * 8 + i;
            float4 o;
            o.x = alpha * (acc[i][0] + bvv[0]);
            o.y = alpha * (acc[i][1] + bvv[1]);
            o.z = alpha * (acc[i][2] + bvv[2]);
            o.w = alpha * (acc[i][3] + bvv[3]);
            *(float4*)(C + (size_t)m * N + n) = o;
        }
    } else {
        const int mm = n >> 10;
        const int rem = n & 1023;
        const int h = rem >> 6;
        const int d = rem & 63;
#pragma unroll
        for (int i = 0; i < 8; ++i) {
            int m = m0 + ty * 8 + i;
            int b_ = m >> 10;
            int t = m & 1023;
            int s = 2 * t + mm;
            float4 o;
            o.x = alpha * (acc[i][0] + bvv[0]);
            o.y = alpha * (acc[i][1] + bvv[1]);
            o.z = alpha * (acc[i][2] + bvv[2]);
            o.w = alpha * (acc[i][3] + bvv[3]);
            *(float4*)(C + ((size_t)((b_ * HH + h) * SS + s)) * HDIM + d) = o;
        }
    }
}

// ---------------------------------------------------------------------------
// Flash attention (fp32), one block per (b, h, 64-row q tile).
// Q: [B*T, E] (already scaled, head h at column h*64)
// Kh/Vh: [B,H,S,HD]; mask: [B,1,T,T]; O: [B*T, E]
// ---------------------------------------------------------------------------
__global__ __launch_bounds__(256) void attn_flash_kernel(
    const float* __restrict__ Q, const float* __restrict__ Kh,
    const float* __restrict__ Vh, const float* __restrict__ mask,
    float* __restrict__ O)
{
    __shared__ __align__(16) float Qs[64][68];   // [d][t]
    __shared__ __align__(16) float KPs[64][68];  // K: [d][s]; then P: [s][t]
    __shared__ __align__(16) float Vs[64][68];   // [s][d]

    const int tid = threadIdx.x;
    const int tx = tid & 15;   // columns (s for QK, d for PV)
    const int ty = tid >> 4;   // rows (t)
    const int t0 = blockIdx.x * 64;
    const int bh = blockIdx.y;
    const int b_ = bh >> 4;
    const int h = bh & 15;

    // Load Q tile transposed into Qs[d][t]
#pragma unroll
    for (int it = 0; it < 4; ++it) {
        int idx = tid + it * 256;          // 0..1023
        int r = idx >> 4;                  // t row 0..63
        int c = (idx & 15) << 2;           // d 0..60
        float4 v = *(const float4*)(Q + (size_t)(b_ * TT + t0 + r) * EE + h * HDIM + c);
        Qs[c + 0][r] = v.x; Qs[c + 1][r] = v.y;
        Qs[c + 2][r] = v.z; Qs[c + 3][r] = v.w;
    }

    float oacc[4][4];
    float mrun[4], lrun[4];
#pragma unroll
    for (int i = 0; i < 4; ++i) {
        mrun[i] = -INFINITY;
        lrun[i] = 0.0f;
#pragma unroll
        for (int j = 0; j < 4; ++j) oacc[i][j] = 0.0f;
    }

    const float* Kbase = Kh + (size_t)(b_ * HH + h) * SS * HDIM;
    const float* Vbase = Vh + (size_t)(b_ * HH + h) * SS * HDIM;

    for (int st = 0; st < SS / 64; ++st) {
        const int s0 = st * 64;
        __syncthreads();  // previous tile's P/V reads complete (also fences Qs on st==0)

        // Load K (transposed -> KPs[d][s]) and V (natural -> Vs[s][d])
#pragma unroll
        for (int it = 0; it < 4; ++it) {
            int idx = tid + it * 256;
            int r = idx >> 4;              // s row 0..63
            int c = (idx & 15) << 2;       // d 0..60
            float4 kv = *(const float4*)(Kbase + (size_t)(s0 + r) * HDIM + c);
            KPs[c + 0][r] = kv.x; KPs[c + 1][r] = kv.y;
            KPs[c + 2][r] = kv.z; KPs[c + 3][r] = kv.w;
            float4 vv = *(const float4*)(Vbase + (size_t)(s0 + r) * HDIM + c);
            *(float4*)&Vs[r][c] = vv;
        }
        __syncthreads();

        // S = Q . K^T   (64x64, k over d=64)
        float sacc[4][4];
#pragma unroll
        for (int i = 0; i < 4; ++i)
#pragma unroll
            for (int j = 0; j < 4; ++j) sacc[i][j] = 0.0f;
#pragma unroll 8
        for (int d = 0; d < HDIM; ++d) {
            float qv[4], kv[4];
            *(float4*)qv = *(const float4*)&Qs[d][ty * 4];
            *(float4*)kv = *(const float4*)&KPs[d][tx * 4];
#pragma unroll
            for (int i = 0; i < 4; ++i)
#pragma unroll
                for (int j = 0; j < 4; ++j)
                    sacc[i][j] = fmaf(qv[i], kv[j], sacc[i][j]);
        }

        // mask add: s tile lies entirely in one MULT region; t2 = s % T
        const int t2b = s0 & (TT - 1);
#pragma unroll
        for (int i = 0; i < 4; ++i) {
            const float* mp = mask + (size_t)(b_ * TT + t0 + ty * 4 + i) * TT + t2b + tx * 4;
            float4 mv = *(const float4*)mp;
            sacc[i][0] += mv.x; sacc[i][1] += mv.y;
            sacc[i][2] += mv.z; sacc[i][3] += mv.w;
        }

        __syncthreads();  // everyone finished reading K from KPs

        // online softmax + write P into KPs[s][t]
#pragma unroll
        for (int i = 0; i < 4; ++i) {
            float rm = fmaxf(fmaxf(sacc[i][0], sacc[i][1]), fmaxf(sacc[i][2], sacc[i][3]));
            rm = fmaxf(rm, __shfl_xor(rm, 1));
            rm = fmaxf(rm, __shfl_xor(rm, 2));
            rm = fmaxf(rm, __shfl_xor(rm, 4));
            rm = fmaxf(rm, __shfl_xor(rm, 8));
            float mnew = fmaxf(mrun[i], rm);
            float scl = __expf(mrun[i] - mnew);  // 0 on first tile (mrun=-inf)
            float p0 = __expf(sacc[i][0] - mnew);
            float p1 = __expf(sacc[i][1] - mnew);
            float p2 = __expf(sacc[i][2] - mnew);
            float p3 = __expf(sacc[i][3] - mnew);
            float rs = (p0 + p1) + (p2 + p3);
            rs += __shfl_xor(rs, 1);
            rs += __shfl_xor(rs, 2);
            rs += __shfl_xor(rs, 4);
            rs += __shfl_xor(rs, 8);
            lrun[i] = lrun[i] * scl + rs;
            mrun[i] = mnew;
#pragma unroll
            for (int j = 0; j < 4; ++j) oacc[i][j] *= scl;
            KPs[tx * 4 + 0][ty * 4 + i] = p0;
            KPs[tx * 4 + 1][ty * 4 + i] = p1;
            KPs[tx * 4 + 2][ty * 4 + i] = p2;
            KPs[tx * 4 + 3][ty * 4 + i] = p3;
        }
        __syncthreads();

        // O += P . V   (64x64, k over s=64)
#pragma unroll 8
        for (int s = 0; s < 64; ++s) {
            float pv[4], vv[4];
            *(float4*)pv = *(const float4*)&KPs[s][ty * 4];
            *(float4*)vv = *(const float4*)&Vs[s][tx * 4];
#pragma unroll
            for (int i = 0; i < 4; ++i)
#pragma unroll
                for (int j = 0; j < 4; ++j)
                    oacc[i][j] = fmaf(pv[i], vv[j], oacc[i][j]);
        }
    }

    // write O[b, t, h*64 + d], normalized
#pragma unroll
    for (int i = 0; i < 4; ++i) {
        float inv = 1.0f / lrun[i];
        float4 o;
        o.x = oacc[i][0] * inv;
        o.y = oacc[i][1] * inv;
        o.z = oacc[i][2] * inv;
        o.w = oacc[i][3] * inv;
        *(float4*)(O + (size_t)(b_ * TT + t0 + ty * 4 + i) * EE + h * HDIM + tx * 4) = o;
    }
}

// ---------------------------------------------------------------------------
extern "C" void kernel_launch(void* const* d_in, const int* in_sizes, int n_in,
                              void* d_out, int out_size, void* d_ws, size_t ws_size,
                              hipStream_t stream)
{
    (void)in_sizes; (void)n_in; (void)out_size; (void)ws_size;

    const float* x    = (const float*)d_in[0];
    const float* mask = (const float*)d_in[1];
    const float* Wq   = (const float*)d_in[2];
    const float* bq   = (const float*)d_in[3];
    const float* Wk   = (const float*)d_in[4];
    const float* bk   = (const float*)d_in[5];
    const float* Wv   = (const float*)d_in[6];
    const float* bv   = (const float*)d_in[7];
    const float* Wo   = (const float*)d_in[8];
    const float* bo   = (const float*)d_in[9];
    float* out = (float*)d_out;

    // workspace layout (floats): qp 4M | kp 8M | vp 8M | ao 4M  = 96 MB
    float* qp = (float*)d_ws;                       // [B*T, E], scaled
    float* kp = qp + (size_t)MROWS * EE;            // [B,H,S,HD]
    float* vp = kp + (size_t)BB * HH * SS * HDIM;   // [B,H,S,HD]
    float* ao = vp + (size_t)BB * HH * SS * HDIM;   // [B*T, E]

    dim3 blk(256);
    // Q projection (scaled, plain layout)
    gemm_bias_kernel<0><<<dim3(MROWS / 128, EE / 64), blk, 0, stream>>>(
        x, Wq, bq, qp, MROWS, EE, EE, SCALEQ);
    // K / V projections (head layout)
    gemm_bias_kernel<1><<<dim3(MROWS / 128, (KVMULT * EE) / 64), blk, 0, stream>>>(
        x, Wk, bk, kp, MROWS, KVMULT * EE, EE, 1.0f);
    gemm_bias_kernel<1><<<dim3(MROWS / 128, (KVMULT * EE) / 64), blk, 0, stream>>>(
        x, Wv, bv, vp, MROWS, KVMULT * EE, EE, 1.0f);
    // attention
    attn_flash_kernel<<<dim3(TT / 64, BB * HH), blk, 0, stream>>>(qp, kp, vp, mask, ao);
    // output projection
    gemm_bias_kernel<0><<<dim3(MROWS / 128, EE / 64), blk, 0, stream>>>(
        ao, Wo, bo, out, MROWS, EE, EE, 1.0f);
}

// Round 2
// 525.513 us; speedup vs baseline: 2.5189x; 2.5189x over previous
//
#include <hip/hip_runtime.h>
#include <math.h>

// Problem constants (fixed by the reference)
#define BB    4
#define TT    1024
#define EE    1024
#define HH    16
#define HDIM  64
#define SS    2048            // T * MULT
#define MROWS 4096            // B * T
#define SCALEQ 0.125f

typedef short  s8v  __attribute__((ext_vector_type(8)));   // 8 bf16 (4 VGPRs)
typedef float  f4v  __attribute__((ext_vector_type(4)));   // 4 fp32 acc

__device__ __forceinline__ unsigned short f2bf(float f) {
    union { float f; unsigned u; } c; c.f = f;
    unsigned u = c.u + 0x7FFFu + ((c.u >> 16) & 1u);   // RNE
    return (unsigned short)(u >> 16);
}
__device__ __forceinline__ float bf2f(unsigned short h) {
    union { unsigned u; float f; } c; c.u = ((unsigned)h) << 16;
    return c.f;
}

// ---------------------------------------------------------------------------
// fp32 -> bf16 convert (grid-stride, float4/ushort4)
// ---------------------------------------------------------------------------
__global__ __launch_bounds__(256) void cvt_bf16_kernel(
    const float* __restrict__ in, unsigned short* __restrict__ out, int n4)
{
    int i = blockIdx.x * blockDim.x + threadIdx.x;
    int stride = gridDim.x * blockDim.x;
    for (; i < n4; i += stride) {
        float4 v = ((const float4*)in)[i];
        ushort4 o;
        o.x = f2bf(v.x); o.y = f2bf(v.y); o.z = f2bf(v.z); o.w = f2bf(v.w);
        ((ushort4*)out)[i] = o;
    }
}

// ---------------------------------------------------------------------------
// bf16 MFMA GEMM: C = alpha * (A @ W^T + bias)
//   A [M,K] bf16 row-major, W [N,K] bf16 row-major.
//   LAYOUT 0: plain C[m*N+n]; OUTF32 picks fp32 vs bf16 output.
//   LAYOUT 1: KV head layout (n->(mm,h,d), m->(b,t), s=2t+mm) -> [B,H,S,HD] bf16
//   LAYOUT 2: rows are features f, cols are tokens xm (A=Wv, W=x) ->
//             V^T layout [B,H,HD,S] bf16; bias indexed by ROW (f).
// 128x128 tile, BK=32, 4 waves each 64x64 via 16 mfma_16x16x32.
// LDS pitch 40 ushorts: frag ds_read_b128 banks land uniform (8 dwords/bank).
// ---------------------------------------------------------------------------
template <int LAYOUT, int OUTF32>
__global__ __launch_bounds__(256, 3) void gemm_mfma_kernel(
    const unsigned short* __restrict__ A, const unsigned short* __restrict__ W,
    const float* __restrict__ bias, void* __restrict__ Cout,
    int M, int N, int K, float alpha)
{
    constexpr int PT = 40;   // ushorts per 32-elt row (+8 pad)
    __shared__ __align__(16) unsigned short As[128 * PT];
    __shared__ __align__(16) unsigned short Bs[128 * PT];

    const int tid   = threadIdx.x;
    const int lane  = tid & 63;
    const int w     = tid >> 6;        // wave 0..3
    const int wm    = (w & 1) * 64;
    const int wn    = (w >> 1) * 64;
    const int col16 = lane & 15;
    const int quad  = lane >> 4;
    const int m0 = blockIdx.x * 128;
    const int n0 = blockIdx.y * 128;

    f4v acc[4][4];
#pragma unroll
    for (int i = 0; i < 4; ++i)
#pragma unroll
        for (int j = 0; j < 4; ++j) acc[i][j] = (f4v)0.0f;

    for (int k0 = 0; k0 < K; k0 += 32) {
        uint4 ar[2], br[2];
#pragma unroll
        for (int it = 0; it < 2; ++it) {
            int idx = tid + it * 256;      // 512 chunks of 8 ushorts
            int r = idx >> 2, c = (idx & 3) * 8;
            ar[it] = *(const uint4*)(A + (size_t)(m0 + r) * K + k0 + c);
            br[it] = *(const uint4*)(W + (size_t)(n0 + r) * K + k0 + c);
        }
        __syncthreads();
#pragma unroll
        for (int it = 0; it < 2; ++it) {
            int idx = tid + it * 256;
            int r = idx >> 2, c = (idx & 3) * 8;
            *(uint4*)(As + r * PT + c) = ar[it];
            *(uint4*)(Bs + r * PT + c) = br[it];
        }
        __syncthreads();

        s8v af[4], bf[4];
#pragma unroll
        for (int i = 0; i < 4; ++i)
            af[i] = *(const s8v*)(As + (wm + i * 16 + col16) * PT + quad * 8);
#pragma unroll
        for (int j = 0; j < 4; ++j)
            bf[j] = *(const s8v*)(Bs + (wn + j * 16 + col16) * PT + quad * 8);
#pragma unroll
        for (int i = 0; i < 4; ++i)
#pragma unroll
            for (int j = 0; j < 4; ++j)
                acc[i][j] = __builtin_amdgcn_mfma_f32_16x16x32_bf16(
                    af[i], bf[j], acc[i][j], 0, 0, 0);
    }

    // epilogue: C row = m0+wm+i*16+quad*4+r, col = n0+wn+j*16+col16
#pragma unroll
    for (int j = 0; j < 4; ++j) {
        const int n = n0 + wn + j * 16 + col16;
        const float bn = (LAYOUT == 2) ? 0.0f : bias[n];
#pragma unroll
        for (int i = 0; i < 4; ++i) {
            const int mb = m0 + wm + i * 16 + quad * 4;
#pragma unroll
            for (int r = 0; r < 4; ++r) {
                const int m = mb + r;
                float c = acc[i][j][r];
                c = (c + ((LAYOUT == 2) ? bias[m] : bn)) * alpha;
                if (LAYOUT == 0) {
                    if (OUTF32) ((float*)Cout)[(size_t)m * N + n] = c;
                    else ((unsigned short*)Cout)[(size_t)m * N + n] = f2bf(c);
                } else if (LAYOUT == 1) {
                    const int mm = n >> 10, h = (n >> 6) & 15, d = n & 63;
                    const int b_ = m >> 10, t = m & 1023;
                    const int s = 2 * t + mm;
                    ((unsigned short*)Cout)[((size_t)(b_ * HH + h) * SS + s) * HDIM + d] = f2bf(c);
                } else { // LAYOUT 2: m = feature f, n = token index
                    const int mm = m >> 10, h = (m >> 6) & 15, d = m & 63;
                    const int b_ = n >> 10, t = n & 1023;
                    const int s = 2 * t + mm;
                    ((unsigned short*)Cout)[((size_t)(b_ * HH + h) * HDIM + d) * SS + s] = f2bf(c);
                }
            }
        }
    }
}

// ---------------------------------------------------------------------------
// Flash attention, bf16 MFMA. Block = (b,h, 64-row q tile), 4 waves x 16 rows.
// Q: [B*T,E] bf16 (pre-scaled); K: [B,H,S,HD] bf16; Vt: [B,H,HD,S] bf16;
// Mb: [B,T,T] bf16 mask; O: [B*T,E] bf16.
// Per s-tile(64): stage K/Vt/mask -> QK^T (8 mfma/wave) -> online softmax ->
// P via LDS (C-layout -> A-layout, m120 pattern) -> PV (8 mfma/wave).
// KPs holds K then is reused for P (aliased; barriers C/D protect).
// ---------------------------------------------------------------------------
__global__ __launch_bounds__(256, 4) void attn_mfma_kernel(
    const unsigned short* __restrict__ Q, const unsigned short* __restrict__ Kh,
    const unsigned short* __restrict__ Vt, const unsigned short* __restrict__ Mb,
    unsigned short* __restrict__ O)
{
    constexpr int PT = 72;   // 64 + 8 pad; 144 B pitch, 16B-aligned, 2-way banks
    __shared__ __align__(16) unsigned short Qs[64 * PT];
    __shared__ __align__(16) unsigned short KPs[64 * PT];  // K tile, then P tile
    __shared__ __align__(16) unsigned short Vs[64 * PT];   // V^T tile [d][s]
    __shared__ __align__(16) unsigned short Ms[64 * PT];   // mask tile [t][t2]

    const int tid   = threadIdx.x;
    const int lane  = tid & 63;
    const int w     = tid >> 6;
    const int col16 = lane & 15;
    const int quad  = lane >> 4;
    const int t0 = blockIdx.x * 64;
    const int bh = blockIdx.y;
    const int b_ = bh >> 4;
    const int h  = bh & 15;

    // stage Q tile once: rows t, 64 cols (head h)
#pragma unroll
    for (int it = 0; it < 2; ++it) {
        int idx = tid + it * 256;
        int r = idx >> 3, c = (idx & 7) * 8;
        *(uint4*)(Qs + r * PT + c) =
            *(const uint4*)(Q + (size_t)(b_ * TT + t0 + r) * EE + h * HDIM + c);
    }

    f4v oacc[4];
    float mrun[4], lrun[4];
#pragma unroll
    for (int r = 0; r < 4; ++r) {
        oacc[r] = (f4v)0.0f;   // index = n-tile, but init all
        mrun[r] = -INFINITY;
        lrun[r] = 0.0f;
    }

    const unsigned short* Kb  = Kh + (size_t)bh * SS * HDIM;
    const unsigned short* Vb  = Vt + (size_t)bh * HDIM * SS;
    const unsigned short* Mbb = Mb + (size_t)b_ * TT * TT;

    for (int s0 = 0; s0 < SS; s0 += 64) {
        __syncthreads();  // (A) prev PV reads of KPs/Vs + mask reads done
        const int t2b = s0 & (TT - 1);
#pragma unroll
        for (int it = 0; it < 2; ++it) {
            int idx = tid + it * 256;
            int r = idx >> 3, c = (idx & 7) * 8;
            *(uint4*)(KPs + r * PT + c) = *(const uint4*)(Kb + (size_t)(s0 + r) * HDIM + c);
            *(uint4*)(Vs  + r * PT + c) = *(const uint4*)(Vb + (size_t)r * SS + s0 + c);
            *(uint4*)(Ms  + r * PT + c) = *(const uint4*)(Mbb + (size_t)(t0 + r) * TT + t2b + c);
        }
        __syncthreads();  // (B)

        // S = Q . K^T  : A[m=t][k=d] from Qs, B[n=s][k=d] from KPs
        f4v sacc[4];
#pragma unroll
        for (int j = 0; j < 4; ++j) sacc[j] = (f4v)0.0f;
#pragma unroll
        for (int ks = 0; ks < 2; ++ks) {
            s8v aq = *(const s8v*)(Qs + (w * 16 + col16) * PT + ks * 32 + quad * 8);
#pragma unroll
            for (int j = 0; j < 4; ++j) {
                s8v bk = *(const s8v*)(KPs + (j * 16 + col16) * PT + ks * 32 + quad * 8);
                sacc[j] = __builtin_amdgcn_mfma_f32_16x16x32_bf16(aq, bk, sacc[j], 0, 0, 0);
            }
        }
        // mask add: C element (row=quad*4+r, col=j*16+col16)
#pragma unroll
        for (int j = 0; j < 4; ++j)
#pragma unroll
            for (int r = 0; r < 4; ++r)
                sacc[j][r] += bf2f(Ms[(w * 16 + quad * 4 + r) * PT + j * 16 + col16]);

        // online softmax per row r (shfl over the 16-lane col group)
#pragma unroll
        for (int r = 0; r < 4; ++r) {
            float vmax = fmaxf(fmaxf(sacc[0][r], sacc[1][r]),
                               fmaxf(sacc[2][r], sacc[3][r]));
            vmax = fmaxf(vmax, __shfl_xor(vmax, 1));
            vmax = fmaxf(vmax, __shfl_xor(vmax, 2));
            vmax = fmaxf(vmax, __shfl_xor(vmax, 4));
            vmax = fmaxf(vmax, __shfl_xor(vmax, 8));
            float mnew = fmaxf(mrun[r], vmax);
            float scl  = __expf(mrun[r] - mnew);  // 0 on first tile
            float rs = 0.0f;
#pragma unroll
            for (int j = 0; j < 4; ++j) {
                float p = __expf(sacc[j][r] - mnew);
                sacc[j][r] = p;
                rs += p;
            }
            rs += __shfl_xor(rs, 1);
            rs += __shfl_xor(rs, 2);
            rs += __shfl_xor(rs, 4);
            rs += __shfl_xor(rs, 8);
            lrun[r] = lrun[r] * scl + rs;
            mrun[r] = mnew;
#pragma unroll
            for (int j = 0; j < 4; ++j) oacc[j][r] *= scl;
        }
        __syncthreads();  // (C) all waves done reading KPs (K) and Ms

        // write P (bf16) to KPs as [t][s]
#pragma unroll
        for (int j = 0; j < 4; ++j)
#pragma unroll
            for (int r = 0; r < 4; ++r)
                KPs[(w * 16 + quad * 4 + r) * PT + j * 16 + col16] = f2bf(sacc[j][r]);
        __syncthreads();  // (D)

        // O += P . V : A[m=t][k=s] from KPs, B[n=d][k=s] from Vs
#pragma unroll
        for (int ks = 0; ks < 2; ++ks) {
            s8v ap = *(const s8v*)(KPs + (w * 16 + col16) * PT + ks * 32 + quad * 8);
#pragma unroll
            for (int j = 0; j < 4; ++j) {
                s8v bv_ = *(const s8v*)(Vs + (j * 16 + col16) * PT + ks * 32 + quad * 8);
                oacc[j] = __builtin_amdgcn_mfma_f32_16x16x32_bf16(ap, bv_, oacc[j], 0, 0, 0);
            }
        }
    }

    // epilogue: normalize and write bf16
#pragma unroll
    for (int r = 0; r < 4; ++r) {
        float inv = 1.0f / lrun[r];
        int t = t0 + w * 16 + quad * 4 + r;
#pragma unroll
        for (int j = 0; j < 4; ++j)
            O[(size_t)(b_ * TT + t) * EE + h * HDIM + j * 16 + col16] =
                f2bf(oacc[j][r] * inv);
    }
}

// ---------------------------------------------------------------------------
extern "C" void kernel_launch(void* const* d_in, const int* in_sizes, int n_in,
                              void* d_out, int out_size, void* d_ws, size_t ws_size,
                              hipStream_t stream)
{
    (void)in_sizes; (void)n_in; (void)out_size; (void)ws_size;

    const float* x    = (const float*)d_in[0];
    const float* mask = (const float*)d_in[1];
    const float* Wq   = (const float*)d_in[2];
    const float* bq   = (const float*)d_in[3];
    const float* Wk   = (const float*)d_in[4];
    const float* bk   = (const float*)d_in[5];
    const float* Wv   = (const float*)d_in[6];
    const float* bv   = (const float*)d_in[7];
    const float* Wo   = (const float*)d_in[8];
    const float* bo   = (const float*)d_in[9];
    float* out = (float*)d_out;

    // workspace carve (ushort units, all 16B aligned). Total ~76 MB.
    unsigned short* xb  = (unsigned short*)d_ws;
    unsigned short* wqb = xb  + (size_t)MROWS * EE;          // 4,194,304
    unsigned short* wkb = wqb + (size_t)EE * EE;             // 1,048,576
    unsigned short* wvb = wkb + (size_t)2 * EE * EE;         // 2,097,152
    unsigned short* wob = wvb + (size_t)2 * EE * EE;         // 2,097,152
    unsigned short* mb  = wob + (size_t)EE * EE;             // 1,048,576
    unsigned short* qp  = mb  + (size_t)BB * TT * TT;        // 4,194,304
    unsigned short* kp  = qp  + (size_t)MROWS * EE;          // 4,194,304
    unsigned short* vt  = kp  + (size_t)BB * HH * SS * HDIM; // 8,388,608
    unsigned short* ao  = vt  + (size_t)BB * HH * SS * HDIM; // 8,388,608

    dim3 blk(256);

    // fp32 -> bf16 conversions
    cvt_bf16_kernel<<<1024, blk, 0, stream>>>(x,    xb,  MROWS * EE / 4);
    cvt_bf16_kernel<<<1024, blk, 0, stream>>>(Wq,   wqb, EE * EE / 4);
    cvt_bf16_kernel<<<1024, blk, 0, stream>>>(Wk,   wkb, 2 * EE * EE / 4);
    cvt_bf16_kernel<<<1024, blk, 0, stream>>>(Wv,   wvb, 2 * EE * EE / 4);
    cvt_bf16_kernel<<<1024, blk, 0, stream>>>(Wo,   wob, EE * EE / 4);
    cvt_bf16_kernel<<<1024, blk, 0, stream>>>(mask, mb,  BB * TT * TT / 4);

    // Q projection (scaled), plain bf16 layout
    gemm_mfma_kernel<0, 0><<<dim3(MROWS / 128, EE / 128), blk, 0, stream>>>(
        xb, wqb, bq, qp, MROWS, EE, EE, SCALEQ);
    // K projection -> head layout [B,H,S,HD]
    gemm_mfma_kernel<1, 0><<<dim3(MROWS / 128, 2 * EE / 128), blk, 0, stream>>>(
        xb, wkb, bk, kp, MROWS, 2 * EE, EE, 1.0f);
    // V projection computed transposed (A=Wv, W=x) -> V^T layout [B,H,HD,S]
    gemm_mfma_kernel<2, 0><<<dim3(2 * EE / 128, MROWS / 128), blk, 0, stream>>>(
        wvb, xb, bv, vt, 2 * EE, MROWS, EE, 1.0f);
    // attention
    attn_mfma_kernel<<<dim3(TT / 64, BB * HH), blk, 0, stream>>>(qp, kp, vt, mb, ao);
    // output projection -> fp32 out
    gemm_mfma_kernel<0, 1><<<dim3(MROWS / 128, EE / 128), blk, 0, stream>>>(
        ao, wob, bo, out, MROWS, EE, EE, 1.0f);
}

// Round 4
// 320.220 us; speedup vs baseline: 4.1337x; 1.6411x over previous
//
#include <hip/hip_runtime.h>
#include <math.h>

// Problem constants (fixed by the reference)
#define BB    4
#define TT    1024
#define EE    1024
#define HH    16
#define HDIM  64
#define SS    2048            // T * MULT
#define MROWS 4096            // B * T
#define SCALEQ 0.125f

typedef short  s8v  __attribute__((ext_vector_type(8)));   // 8 bf16 (4 VGPRs)
typedef float  f4v  __attribute__((ext_vector_type(4)));   // 4 fp32 acc

__device__ __forceinline__ unsigned short f2bf(float f) {
    union { float f; unsigned u; } c; c.f = f;
    unsigned u = c.u + 0x7FFFu + ((c.u >> 16) & 1u);   // RNE
    return (unsigned short)(u >> 16);
}
__device__ __forceinline__ float bf2f(unsigned short h) {
    union { unsigned u; float f; } c; c.u = ((unsigned)h) << 16;
    return c.f;
}

// async global->LDS, 16B per lane. LDS dest = wave-uniform base + lane*16.
// Proper addrspacecast (generic -> AS3), not integer truncation.
__device__ __forceinline__ void async16(const void* g, void* l) {
    __builtin_amdgcn_global_load_lds(
        (const __attribute__((address_space(1))) unsigned int*)g,
        (__attribute__((address_space(3))) unsigned int*)l,
        16, 0, 0);
}

// ---------------------------------------------------------------------------
// Fused fp32->bf16 convert: x, Wq, Wk, Wv, Wo in one launch (float4 granules).
// Segment sizes (float4): x 1048576 | wq 262144 | wk 524288 | wv 524288 | wo 262144
// ---------------------------------------------------------------------------
__global__ __launch_bounds__(256) void cvt5_kernel(
    const float* __restrict__ x,  const float* __restrict__ wq,
    const float* __restrict__ wk, const float* __restrict__ wv,
    const float* __restrict__ wo,
    unsigned short* __restrict__ xb,  unsigned short* __restrict__ wqb,
    unsigned short* __restrict__ wkb, unsigned short* __restrict__ wvb,
    unsigned short* __restrict__ wob)
{
    const int total = 2621440;
    int i = blockIdx.x * 256 + threadIdx.x;
    const int stride = gridDim.x * 256;
    for (; i < total; i += stride) {
        const float* s; unsigned short* d; int off;
        if (i < 1048576)      { s = x;  d = xb;  off = i; }
        else if (i < 1310720) { s = wq; d = wqb; off = i - 1048576; }
        else if (i < 1835008) { s = wk; d = wkb; off = i - 1310720; }
        else if (i < 2359296) { s = wv; d = wvb; off = i - 1835008; }
        else                  { s = wo; d = wob; off = i - 2359296; }
        float4 v = ((const float4*)s)[off];
        ushort4 o;
        o.x = f2bf(v.x); o.y = f2bf(v.y); o.z = f2bf(v.z); o.w = f2bf(v.w);
        ((ushort4*)d)[off] = o;
    }
}

// ---------------------------------------------------------------------------
// Shared GEMM K-loop body (m97-style): 128x128 tile, BK=32, global_load_lds
// width=16 into unpadded LDS [128][32] ushort (64B rows), 2 barriers/iter.
// 4 waves, each 64x64 (4x4 of mfma_16x16x32_bf16). acc in AGPR/VGPR.
// Staging math: lane chunk f=(it*4+w)*64+lane; dest ushort offset 8*f equals
// row (f>>2) * 32 + (f&3)*8 -> exactly [r][g] of the unpadded tile.
// ---------------------------------------------------------------------------
#define GEMM_KLOOP(Aptr, Wptr, Ksz)                                            \
    for (int k0 = 0; k0 < (Ksz); k0 += 32) {                                   \
        _Pragma("unroll")                                                      \
        for (int it = 0; it < 2; ++it) {                                       \
            int f = (it * 4 + w) * 64 + lane;                                  \
            int r = f >> 2, g = (f & 3) * 8;                                   \
            async16((Aptr) + (size_t)(m0 + r) * (Ksz) + k0 + g,                \
                    As + (it * 4 + w) * 512);                                  \
            async16((Wptr) + (size_t)(n0 + r) * (Ksz) + k0 + g,                \
                    Bs + (it * 4 + w) * 512);                                  \
        }                                                                      \
        __syncthreads();                                                       \
        s8v af[4], bf[4];                                                      \
        _Pragma("unroll")                                                      \
        for (int i = 0; i < 4; ++i)                                            \
            af[i] = *(const s8v*)(As + (wm + i * 16 + col16) * 32 + quad * 8); \
        _Pragma("unroll")                                                      \
        for (int j = 0; j < 4; ++j)                                            \
            bf[j] = *(const s8v*)(Bs + (wn + j * 16 + col16) * 32 + quad * 8); \
        _Pragma("unroll")                                                      \
        for (int i = 0; i < 4; ++i)                                            \
            _Pragma("unroll")                                                  \
            for (int j = 0; j < 4; ++j)                                        \
                acc[i][j] = __builtin_amdgcn_mfma_f32_16x16x32_bf16(           \
                    af[i], bf[j], acc[i][j], 0, 0, 0);                         \
        __syncthreads();                                                       \
    }

// ---------------------------------------------------------------------------
// Fused Q+K projection: A=x [4096,1024]; blockIdx.y<8 -> Q (scale, plain bf16
// into qp), else -> K (head layout [B,H,S,HD] into kp). Grid (32, 24).
// ---------------------------------------------------------------------------
__global__ __launch_bounds__(256, 3) void gemm_qk_kernel(
    const unsigned short* __restrict__ X,  const unsigned short* __restrict__ Wq,
    const unsigned short* __restrict__ Wk, const float* __restrict__ bq,
    const float* __restrict__ bk, unsigned short* __restrict__ qp,
    unsigned short* __restrict__ kp)
{
    __shared__ __align__(16) unsigned short As[128 * 32];
    __shared__ __align__(16) unsigned short Bs[128 * 32];

    const int tid = threadIdx.x;
    const int lane = tid & 63, w = tid >> 6;
    const int wm = (w & 1) * 64, wn = (w >> 1) * 64;
    const int col16 = lane & 15, quad = lane >> 4;
    const int m0 = blockIdx.x * 128;
    const bool isQ = blockIdx.y < 8;
    const int n0 = blockIdx.y * 128;
    const unsigned short* Wrow = isQ ? Wq + (size_t)n0 * EE
                                     : Wk + (size_t)(n0 - EE) * EE;

    f4v acc[4][4];
#pragma unroll
    for (int i = 0; i < 4; ++i)
#pragma unroll
        for (int j = 0; j < 4; ++j) acc[i][j] = (f4v)0.0f;

    for (int k0 = 0; k0 < EE; k0 += 32) {
#pragma unroll
        for (int it = 0; it < 2; ++it) {
            int f = (it * 4 + w) * 64 + lane;
            int r = f >> 2, g = (f & 3) * 8;
            async16(X + (size_t)(m0 + r) * EE + k0 + g, As + (it * 4 + w) * 512);
            async16(Wrow + (size_t)r * EE + k0 + g, Bs + (it * 4 + w) * 512);
        }
        __syncthreads();
        s8v af[4], bf[4];
#pragma unroll
        for (int i = 0; i < 4; ++i)
            af[i] = *(const s8v*)(As + (wm + i * 16 + col16) * 32 + quad * 8);
#pragma unroll
        for (int j = 0; j < 4; ++j)
            bf[j] = *(const s8v*)(Bs + (wn + j * 16 + col16) * 32 + quad * 8);
#pragma unroll
        for (int i = 0; i < 4; ++i)
#pragma unroll
            for (int j = 0; j < 4; ++j)
                acc[i][j] = __builtin_amdgcn_mfma_f32_16x16x32_bf16(
                    af[i], bf[j], acc[i][j], 0, 0, 0);
        __syncthreads();
    }

#pragma unroll
    for (int j = 0; j < 4; ++j) {
        const int n = n0 + wn + j * 16 + col16;           // global n in [0,3072)
        const float bn = isQ ? bq[n] : bk[n - EE];
#pragma unroll
        for (int i = 0; i < 4; ++i) {
            const int mb = m0 + wm + i * 16 + quad * 4;
#pragma unroll
            for (int r = 0; r < 4; ++r) {
                const int m = mb + r;
                float c = acc[i][j][r] + bn;
                if (isQ) {
                    qp[(size_t)m * EE + n] = f2bf(c * SCALEQ);
                } else {
                    const int nk = n - EE;
                    const int mm = nk >> 10, h = (nk >> 6) & 15, d = nk & 63;
                    const int b_ = m >> 10, t = m & 1023;
                    const int s = 2 * t + mm;
                    kp[((size_t)(b_ * HH + h) * SS + s) * HDIM + d] = f2bf(c);
                }
            }
        }
    }
}

// ---------------------------------------------------------------------------
// General GEMM C = alpha*(A @ W^T + bias):
//   LAYOUT 0: plain C[m*Nsz+n] (OUTF32 picks fp32/bf16)
//   LAYOUT 2: V^T: A=Wv (rows f), W=x (rows token); writes [B,H,HD,S] bf16,
//             bias indexed by row m (=f).
// ---------------------------------------------------------------------------
template <int LAYOUT, int OUTF32, int Ksz, int Nsz>
__global__ __launch_bounds__(256, 3) void gemm_mfma_kernel(
    const unsigned short* __restrict__ A, const unsigned short* __restrict__ W,
    const float* __restrict__ bias, void* __restrict__ Cout, float alpha)
{
    __shared__ __align__(16) unsigned short As[128 * 32];
    __shared__ __align__(16) unsigned short Bs[128 * 32];

    const int tid = threadIdx.x;
    const int lane = tid & 63, w = tid >> 6;
    const int wm = (w & 1) * 64, wn = (w >> 1) * 64;
    const int col16 = lane & 15, quad = lane >> 4;
    const int m0 = blockIdx.x * 128;
    const int n0 = blockIdx.y * 128;

    f4v acc[4][4];
#pragma unroll
    for (int i = 0; i < 4; ++i)
#pragma unroll
        for (int j = 0; j < 4; ++j) acc[i][j] = (f4v)0.0f;

    GEMM_KLOOP(A, W, Ksz)

#pragma unroll
    for (int j = 0; j < 4; ++j) {
        const int n = n0 + wn + j * 16 + col16;
        const float bn = (LAYOUT == 2) ? 0.0f : bias[n];
#pragma unroll
        for (int i = 0; i < 4; ++i) {
            const int mb = m0 + wm + i * 16 + quad * 4;
#pragma unroll
            for (int r = 0; r < 4; ++r) {
                const int m = mb + r;
                float c = (acc[i][j][r] + ((LAYOUT == 2) ? bias[m] : bn)) * alpha;
                if (LAYOUT == 0) {
                    if (OUTF32) ((float*)Cout)[(size_t)m * Nsz + n] = c;
                    else ((unsigned short*)Cout)[(size_t)m * Nsz + n] = f2bf(c);
                } else {  // LAYOUT 2: m = feature f, n = token
                    const int mm = m >> 10, h = (m >> 6) & 15, d = m & 63;
                    const int b_ = n >> 10, t = n & 1023;
                    const int s = 2 * t + mm;
                    ((unsigned short*)Cout)[((size_t)(b_ * HH + h) * HDIM + d) * SS + s] = f2bf(c);
                }
            }
        }
    }
}

// ---------------------------------------------------------------------------
// Flash attention, bf16 MFMA, S^T formulation.
// Per s-tile: S^T = K.Q^T (C-layout: lane holds 16 s-values of ONE
// t = w*16+col16) -> online softmax (2 shfls per reduction) -> P store as
// 4x ds_write_b64 into rows w*16+col16 -> O += P.V^T.
// Mask read directly from global fp32. 4 blocks/CU.
// ---------------------------------------------------------------------------
__global__ __launch_bounds__(256, 4) void attn_mfma_kernel(
    const unsigned short* __restrict__ Q, const unsigned short* __restrict__ Kh,
    const unsigned short* __restrict__ Vt, const float* __restrict__ Mf,
    unsigned short* __restrict__ O)
{
    constexpr int PT = 72;   // 144B pitch, 16B aligned
    __shared__ __align__(16) unsigned short Qs[64 * PT];
    __shared__ __align__(16) unsigned short KPs[64 * PT];  // K tile, then P tile
    __shared__ __align__(16) unsigned short Vs[64 * PT];   // V^T tile [d][s]

    const int tid = threadIdx.x;
    const int lane = tid & 63, w = tid >> 6;
    const int col16 = lane & 15, quad = lane >> 4;
    const int t0 = blockIdx.x * 64;
    const int bh = blockIdx.y;
    const int b_ = bh >> 4, h = bh & 15;

    // stage Q tile [t][d]
#pragma unroll
    for (int it = 0; it < 2; ++it) {
        int idx = tid + it * 256;
        int r = idx >> 3, c = (idx & 7) * 8;
        *(uint4*)(Qs + r * PT + c) =
            *(const uint4*)(Q + (size_t)(b_ * TT + t0 + r) * EE + h * HDIM + c);
    }

    f4v oacc[4];
#pragma unroll
    for (int jd = 0; jd < 4; ++jd) oacc[jd] = (f4v)0.0f;
    float mrun = -INFINITY, lrun = 0.0f;

    const unsigned short* Kb = Kh + (size_t)bh * SS * HDIM;
    const unsigned short* Vb = Vt + (size_t)bh * HDIM * SS;
    const float* Mrow = Mf + ((size_t)b_ * TT + t0 + w * 16 + col16) * TT;

    for (int s0 = 0; s0 < SS; s0 += 64) {
        __syncthreads();  // (A) prev PV reads done
#pragma unroll
        for (int it = 0; it < 2; ++it) {
            int idx = tid + it * 256;
            int r = idx >> 3, c = (idx & 7) * 8;
            *(uint4*)(KPs + r * PT + c) = *(const uint4*)(Kb + (size_t)(s0 + r) * HDIM + c);
            *(uint4*)(Vs  + r * PT + c) = *(const uint4*)(Vb + (size_t)r * SS + s0 + c);
        }
        __syncthreads();  // (B)

        // S^T = K . Q^T : A[m=s][k=d] from KPs, B[n=t][k=d] from Qs
        f4v sacc[4];
#pragma unroll
        for (int js = 0; js < 4; ++js) sacc[js] = (f4v)0.0f;
#pragma unroll
        for (int ks = 0; ks < 2; ++ks) {
            s8v bq_ = *(const s8v*)(Qs + (w * 16 + col16) * PT + ks * 32 + quad * 8);
#pragma unroll
            for (int js = 0; js < 4; ++js) {
                s8v ak = *(const s8v*)(KPs + (js * 16 + col16) * PT + ks * 32 + quad * 8);
                sacc[js] = __builtin_amdgcn_mfma_f32_16x16x32_bf16(ak, bq_, sacc[js], 0, 0, 0);
            }
        }

        // mask add (fp32, direct from global): row t (this lane's), col s&1023
        const int t2b = s0 & (TT - 1);
#pragma unroll
        for (int js = 0; js < 4; ++js) {
            float4 mv = *(const float4*)(Mrow + t2b + js * 16 + quad * 4);
            sacc[js][0] += mv.x; sacc[js][1] += mv.y;
            sacc[js][2] += mv.z; sacc[js][3] += mv.w;
        }

        // online softmax over s for this lane's t (lane holds 16 s-partials)
        float tmax = -INFINITY;
#pragma unroll
        for (int js = 0; js < 4; ++js)
#pragma unroll
            for (int r = 0; r < 4; ++r) tmax = fmaxf(tmax, sacc[js][r]);
        tmax = fmaxf(tmax, __shfl_xor(tmax, 16));
        tmax = fmaxf(tmax, __shfl_xor(tmax, 32));
        const float mnew = fmaxf(mrun, tmax);
        const float scl = __expf(mrun - mnew);   // 0 on first tile
        float rs = 0.0f;
#pragma unroll
        for (int js = 0; js < 4; ++js)
#pragma unroll
            for (int r = 0; r < 4; ++r) {
                float p = __expf(sacc[js][r] - mnew);
                sacc[js][r] = p;
                rs += p;
            }
        rs += __shfl_xor(rs, 16);
        rs += __shfl_xor(rs, 32);
        lrun = lrun * scl + rs;
        mrun = mnew;

        // rescale O: oacc row t_local = quad*4+r; scl lives at lane col16=t_local
        float sclr[4];
#pragma unroll
        for (int r = 0; r < 4; ++r) sclr[r] = __shfl(scl, quad * 4 + r);
#pragma unroll
        for (int jd = 0; jd < 4; ++jd)
#pragma unroll
            for (int r = 0; r < 4; ++r) oacc[jd][r] *= sclr[r];

        __syncthreads();  // (C) all waves done reading K from KPs

        // store P[t][s] bf16: lane holds P^T[s=js*16+quad*4+r][t=w*16+col16]
        // -> row (w*16+col16), 4 consecutive s per b64 write
#pragma unroll
        for (int js = 0; js < 4; ++js) {
            unsigned p01 = (unsigned)f2bf(sacc[js][0]) | ((unsigned)f2bf(sacc[js][1]) << 16);
            unsigned p23 = (unsigned)f2bf(sacc[js][2]) | ((unsigned)f2bf(sacc[js][3]) << 16);
            *(uint2*)(KPs + (size_t)(w * 16 + col16) * PT + js * 16 + quad * 4) =
                make_uint2(p01, p23);
        }
        __syncthreads();  // (D)

        // O += P . V : A[m=t][k=s] from KPs(P), B[n=d][k=s] from Vs
#pragma unroll
        for (int ks = 0; ks < 2; ++ks) {
            s8v ap = *(const s8v*)(KPs + (w * 16 + col16) * PT + ks * 32 + quad * 8);
#pragma unroll
            for (int jd = 0; jd < 4; ++jd) {
                s8v bv_ = *(const s8v*)(Vs + (jd * 16 + col16) * PT + ks * 32 + quad * 8);
                oacc[jd] = __builtin_amdgcn_mfma_f32_16x16x32_bf16(ap, bv_, oacc[jd], 0, 0, 0);
            }
        }
    }

    // epilogue: normalize (gather 1/l for row t_local=quad*4+r) and write bf16
    const float inv = 1.0f / lrun;
    float invr[4];
#pragma unroll
    for (int r = 0; r < 4; ++r) invr[r] = __shfl(inv, quad * 4 + r);
#pragma unroll
    for (int r = 0; r < 4; ++r) {
        const int t = t0 + w * 16 + quad * 4 + r;
#pragma unroll
        for (int jd = 0; jd < 4; ++jd)
            O[(size_t)(b_ * TT + t) * EE + h * HDIM + jd * 16 + col16] =
                f2bf(oacc[jd][r] * invr[r]);
    }
}

// ---------------------------------------------------------------------------
extern "C" void kernel_launch(void* const* d_in, const int* in_sizes, int n_in,
                              void* d_out, int out_size, void* d_ws, size_t ws_size,
                              hipStream_t stream)
{
    (void)in_sizes; (void)n_in; (void)out_size; (void)ws_size;

    const float* x    = (const float*)d_in[0];
    const float* mask = (const float*)d_in[1];
    const float* Wq   = (const float*)d_in[2];
    const float* bq   = (const float*)d_in[3];
    const float* Wk   = (const float*)d_in[4];
    const float* bk   = (const float*)d_in[5];
    const float* Wv   = (const float*)d_in[6];
    const float* bv   = (const float*)d_in[7];
    const float* Wo   = (const float*)d_in[8];
    const float* bo   = (const float*)d_in[9];
    float* out = (float*)d_out;

    // workspace carve (ushort units): 30M ushorts = 60 MB
    unsigned short* xb  = (unsigned short*)d_ws;
    unsigned short* wqb = xb  + (size_t)MROWS * EE;          // 4M
    unsigned short* wkb = wqb + (size_t)EE * EE;             // 1M
    unsigned short* wvb = wkb + (size_t)2 * EE * EE;         // 2M
    unsigned short* wob = wvb + (size_t)2 * EE * EE;         // 2M
    unsigned short* qp  = wob + (size_t)EE * EE;             // 1M
    unsigned short* kp  = qp  + (size_t)MROWS * EE;          // 4M
    unsigned short* vt  = kp  + (size_t)BB * HH * SS * HDIM; // 8M
    unsigned short* ao  = vt  + (size_t)BB * HH * SS * HDIM; // 8M

    dim3 blk(256);

    // fused fp32->bf16 conversion (x + 4 weights)
    cvt5_kernel<<<4096, blk, 0, stream>>>(x, Wq, Wk, Wv, Wo,
                                          xb, wqb, wkb, wvb, wob);
    // fused Q+K projection
    gemm_qk_kernel<<<dim3(32, 24), blk, 0, stream>>>(xb, wqb, wkb, bq, bk, qp, kp);
    // V projection computed transposed (A=Wv, W=x) -> V^T [B,H,HD,S]
    gemm_mfma_kernel<2, 0, EE, MROWS><<<dim3(16, 32), blk, 0, stream>>>(
        wvb, xb, bv, vt, 1.0f);
    // attention (mask read directly as fp32)
    attn_mfma_kernel<<<dim3(TT / 64, BB * HH), blk, 0, stream>>>(qp, kp, vt, mask, ao);
    // output projection -> fp32 out
    gemm_mfma_kernel<0, 1, EE, EE><<<dim3(32, 8), blk, 0, stream>>>(
        ao, wob, bo, out, 1.0f);
}

// Round 5
// 287.701 us; speedup vs baseline: 4.6009x; 1.1130x over previous
//
#include <hip/hip_runtime.h>
#include <math.h>

// Problem constants (fixed by the reference)
#define BB    4
#define TT    1024
#define EE    1024
#define HH    16
#define HDIM  64
#define SS    2048            // T * MULT
#define MROWS 4096            // B * T
#define SCALEQ 0.125f

typedef short  s8v  __attribute__((ext_vector_type(8)));   // 8 bf16 (4 VGPRs)
typedef float  f4v  __attribute__((ext_vector_type(4)));   // 4 fp32 acc

__device__ __forceinline__ unsigned short f2bf(float f) {
    union { float f; unsigned u; } c; c.f = f;
    unsigned u = c.u + 0x7FFFu + ((c.u >> 16) & 1u);   // RNE
    return (unsigned short)(u >> 16);
}
__device__ __forceinline__ float bf2f(unsigned short h) {
    union { unsigned u; float f; } c; c.u = ((unsigned)h) << 16;
    return c.f;
}

// async global->LDS, 16B per lane. LDS dest = wave-uniform base + lane*16.
__device__ __forceinline__ void async16(const void* g, void* l) {
    __builtin_amdgcn_global_load_lds(
        (const __attribute__((address_space(1))) unsigned int*)g,
        (__attribute__((address_space(3))) unsigned int*)l,
        16, 0, 0);
}

// ---------------------------------------------------------------------------
// Fused fp32->bf16 convert: x, Wq, Wk, Wv, Wo, mask in one launch.
// float4 segment sizes: x 1048576 | wq 262144 | wk 524288 | wv 524288 |
//                       wo 262144 | mask 1048576  (total 3670016)
// ---------------------------------------------------------------------------
__global__ __launch_bounds__(256) void cvt6_kernel(
    const float* __restrict__ x,  const float* __restrict__ wq,
    const float* __restrict__ wk, const float* __restrict__ wv,
    const float* __restrict__ wo, const float* __restrict__ mk,
    unsigned short* __restrict__ xb,  unsigned short* __restrict__ wqb,
    unsigned short* __restrict__ wkb, unsigned short* __restrict__ wvb,
    unsigned short* __restrict__ wob, unsigned short* __restrict__ mbb)
{
    const int total = 3670016;
    int i = blockIdx.x * 256 + threadIdx.x;
    const int stride = gridDim.x * 256;
    for (; i < total; i += stride) {
        const float* s; unsigned short* d; int off;
        if (i < 1048576)      { s = x;  d = xb;  off = i; }
        else if (i < 1310720) { s = wq; d = wqb; off = i - 1048576; }
        else if (i < 1835008) { s = wk; d = wkb; off = i - 1310720; }
        else if (i < 2359296) { s = wv; d = wvb; off = i - 1835008; }
        else if (i < 2621440) { s = wo; d = wob; off = i - 2359296; }
        else                  { s = mk; d = mbb; off = i - 2621440; }
        float4 v = ((const float4*)s)[off];
        ushort4 o;
        o.x = f2bf(v.x); o.y = f2bf(v.y); o.z = f2bf(v.z); o.w = f2bf(v.w);
        ((ushort4*)d)[off] = o;
    }
}

// ---------------------------------------------------------------------------
// Shared GEMM K-loop body (m97-style): 128x128 tile, BK=32, global_load_lds
// width=16 into unpadded LDS [128][32] ushort (64B rows), 2 barriers/iter.
// ---------------------------------------------------------------------------
#define GEMM_KLOOP(Aptr, Wptr, Ksz)                                            \
    for (int k0 = 0; k0 < (Ksz); k0 += 32) {                                   \
        _Pragma("unroll")                                                      \
        for (int it = 0; it < 2; ++it) {                                       \
            int f = (it * 4 + w) * 64 + lane;                                  \
            int r = f >> 2, g = (f & 3) * 8;                                   \
            async16((Aptr) + (size_t)(m0 + r) * (Ksz) + k0 + g,                \
                    As + (it * 4 + w) * 512);                                  \
            async16((Wptr) + (size_t)(n0 + r) * (Ksz) + k0 + g,                \
                    Bs + (it * 4 + w) * 512);                                  \
        }                                                                      \
        __syncthreads();                                                       \
        s8v af[4], bf[4];                                                      \
        _Pragma("unroll")                                                      \
        for (int i = 0; i < 4; ++i)                                            \
            af[i] = *(const s8v*)(As + (wm + i * 16 + col16) * 32 + quad * 8); \
        _Pragma("unroll")                                                      \
        for (int j = 0; j < 4; ++j)                                            \
            bf[j] = *(const s8v*)(Bs + (wn + j * 16 + col16) * 32 + quad * 8); \
        _Pragma("unroll")                                                      \
        for (int i = 0; i < 4; ++i)                                            \
            _Pragma("unroll")                                                  \
            for (int j = 0; j < 4; ++j)                                        \
                acc[i][j] = __builtin_amdgcn_mfma_f32_16x16x32_bf16(           \
                    af[i], bf[j], acc[i][j], 0, 0, 0);                         \
        __syncthreads();                                                       \
    }

// ---------------------------------------------------------------------------
// Fused Q+K projection: A=x [4096,1024]; blockIdx.y<8 -> Q (scale, plain bf16
// into qp), else -> K (head layout [B,H,S,HD] into kp). Grid (32, 24).
// ---------------------------------------------------------------------------
__global__ __launch_bounds__(256, 3) void gemm_qk_kernel(
    const unsigned short* __restrict__ X,  const unsigned short* __restrict__ Wq,
    const unsigned short* __restrict__ Wk, const float* __restrict__ bq,
    const float* __restrict__ bk, unsigned short* __restrict__ qp,
    unsigned short* __restrict__ kp)
{
    __shared__ __align__(16) unsigned short As[128 * 32];
    __shared__ __align__(16) unsigned short Bs[128 * 32];

    const int tid = threadIdx.x;
    const int lane = tid & 63, w = tid >> 6;
    const int wm = (w & 1) * 64, wn = (w >> 1) * 64;
    const int col16 = lane & 15, quad = lane >> 4;
    const int m0 = blockIdx.x * 128;
    const bool isQ = blockIdx.y < 8;
    const int n0 = blockIdx.y * 128;
    const unsigned short* Wrow = isQ ? Wq + (size_t)n0 * EE
                                     : Wk + (size_t)(n0 - EE) * EE;

    f4v acc[4][4];
#pragma unroll
    for (int i = 0; i < 4; ++i)
#pragma unroll
        for (int j = 0; j < 4; ++j) acc[i][j] = (f4v)0.0f;

    for (int k0 = 0; k0 < EE; k0 += 32) {
#pragma unroll
        for (int it = 0; it < 2; ++it) {
            int f = (it * 4 + w) * 64 + lane;
            int r = f >> 2, g = (f & 3) * 8;
            async16(X + (size_t)(m0 + r) * EE + k0 + g, As + (it * 4 + w) * 512);
            async16(Wrow + (size_t)r * EE + k0 + g, Bs + (it * 4 + w) * 512);
        }
        __syncthreads();
        s8v af[4], bf[4];
#pragma unroll
        for (int i = 0; i < 4; ++i)
            af[i] = *(const s8v*)(As + (wm + i * 16 + col16) * 32 + quad * 8);
#pragma unroll
        for (int j = 0; j < 4; ++j)
            bf[j] = *(const s8v*)(Bs + (wn + j * 16 + col16) * 32 + quad * 8);
#pragma unroll
        for (int i = 0; i < 4; ++i)
#pragma unroll
            for (int j = 0; j < 4; ++j)
                acc[i][j] = __builtin_amdgcn_mfma_f32_16x16x32_bf16(
                    af[i], bf[j], acc[i][j], 0, 0, 0);
        __syncthreads();
    }

#pragma unroll
    for (int j = 0; j < 4; ++j) {
        const int n = n0 + wn + j * 16 + col16;           // global n in [0,3072)
        const float bn = isQ ? bq[n] : bk[n - EE];
#pragma unroll
        for (int i = 0; i < 4; ++i) {
            const int mb = m0 + wm + i * 16 + quad * 4;
#pragma unroll
            for (int r = 0; r < 4; ++r) {
                const int m = mb + r;
                float c = acc[i][j][r] + bn;
                if (isQ) {
                    qp[(size_t)m * EE + n] = f2bf(c * SCALEQ);
                } else {
                    const int nk = n - EE;
                    const int mm = nk >> 10, h = (nk >> 6) & 15, d = nk & 63;
                    const int b_ = m >> 10, t = m & 1023;
                    const int s = 2 * t + mm;
                    kp[((size_t)(b_ * HH + h) * SS + s) * HDIM + d] = f2bf(c);
                }
            }
        }
    }
}

// ---------------------------------------------------------------------------
// General GEMM C = alpha*(A @ W^T + bias):
//   LAYOUT 0: plain C[m*Nsz+n] (OUTF32 picks fp32/bf16)
//   LAYOUT 2: V^T: A=Wv (rows f), W=x (rows token); writes [B,H,HD,S] bf16,
//             bias indexed by row m (=f).
// ---------------------------------------------------------------------------
template <int LAYOUT, int OUTF32, int Ksz, int Nsz>
__global__ __launch_bounds__(256, 3) void gemm_mfma_kernel(
    const unsigned short* __restrict__ A, const unsigned short* __restrict__ W,
    const float* __restrict__ bias, void* __restrict__ Cout, float alpha)
{
    __shared__ __align__(16) unsigned short As[128 * 32];
    __shared__ __align__(16) unsigned short Bs[128 * 32];

    const int tid = threadIdx.x;
    const int lane = tid & 63, w = tid >> 6;
    const int wm = (w & 1) * 64, wn = (w >> 1) * 64;
    const int col16 = lane & 15, quad = lane >> 4;
    const int m0 = blockIdx.x * 128;
    const int n0 = blockIdx.y * 128;

    f4v acc[4][4];
#pragma unroll
    for (int i = 0; i < 4; ++i)
#pragma unroll
        for (int j = 0; j < 4; ++j) acc[i][j] = (f4v)0.0f;

    GEMM_KLOOP(A, W, Ksz)

#pragma unroll
    for (int j = 0; j < 4; ++j) {
        const int n = n0 + wn + j * 16 + col16;
        const float bn = (LAYOUT == 2) ? 0.0f : bias[n];
#pragma unroll
        for (int i = 0; i < 4; ++i) {
            const int mb = m0 + wm + i * 16 + quad * 4;
#pragma unroll
            for (int r = 0; r < 4; ++r) {
                const int m = mb + r;
                float c = (acc[i][j][r] + ((LAYOUT == 2) ? bias[m] : bn)) * alpha;
                if (LAYOUT == 0) {
                    if (OUTF32) ((float*)Cout)[(size_t)m * Nsz + n] = c;
                    else ((unsigned short*)Cout)[(size_t)m * Nsz + n] = f2bf(c);
                } else {  // LAYOUT 2: m = feature f, n = token
                    const int mm = m >> 10, h = (m >> 6) & 15, d = m & 63;
                    const int b_ = n >> 10, t = n & 1023;
                    const int s = 2 * t + mm;
                    ((unsigned short*)Cout)[((size_t)(b_ * HH + h) * HDIM + d) * SS + s] = f2bf(c);
                }
            }
        }
    }
}

// ---------------------------------------------------------------------------
// Flash attention v2: bf16 MFMA, S^T formulation, MULT-paired s-tiles.
// One iteration handles s in {t2b..t2b+63} (half0) and {1024+t2b..} (half1),
// which share mask columns t2b..t2b+63 -> mask staged once (bf16, LDS).
// 16 iterations, 32 MFMA per 4 barriers. LDS 6x(64x68) bf16 = 52.2 KB
// -> 3 blocks/CU. XCD swizzle: gid%8 = virtual XCD, 8 consecutive bh per XCD
// -> K/V (4 MB) + mask slice (2 MB) ~L2-resident per XCD.
// ---------------------------------------------------------------------------
__global__ __launch_bounds__(256, 3) void attn_mfma2_kernel(
    const unsigned short* __restrict__ Q, const unsigned short* __restrict__ Kh,
    const unsigned short* __restrict__ Vt, const unsigned short* __restrict__ Mb,
    unsigned short* __restrict__ O)
{
    constexpr int PT = 68;   // 136B pitch: uniform banks for b128/b64 patterns
    __shared__ __align__(16) unsigned short Qs[64 * PT];
    __shared__ __align__(16) unsigned short K0[64 * PT];  // K half0, then P0
    __shared__ __align__(16) unsigned short K1[64 * PT];  // K half1, then P1
    __shared__ __align__(16) unsigned short V0[64 * PT];  // V^T half0 [d][s]
    __shared__ __align__(16) unsigned short V1[64 * PT];  // V^T half1 [d][s]
    __shared__ __align__(16) unsigned short Ms[64 * PT];  // mask [t][t2] bf16

    const int tid = threadIdx.x;
    const int lane = tid & 63, w = tid >> 6;
    const int col16 = lane & 15, quad = lane >> 4;

    // XCD swizzle: v = gid&7 (round-robin XCD), bh = v*8 + (j>>4), t0 = (j&15)*64
    const int gid = blockIdx.x;
    const int v = gid & 7, j = gid >> 3;
    const int bh = v * 8 + (j >> 4);
    const int t0 = (j & 15) * 64;
    const int b_ = bh >> 4, h = bh & 15;

    // stage Q tile [t][d]
#pragma unroll
    for (int it = 0; it < 2; ++it) {
        int idx = tid + it * 256;
        int r = idx >> 3, c = (idx & 7) * 8;
        *(uint4*)(Qs + r * PT + c) =
            *(const uint4*)(Q + (size_t)(b_ * TT + t0 + r) * EE + h * HDIM + c);
    }

    f4v oacc[4];
#pragma unroll
    for (int jd = 0; jd < 4; ++jd) oacc[jd] = (f4v)0.0f;
    float mrun = -INFINITY, lrun = 0.0f;

    const unsigned short* Kb  = Kh + (size_t)bh * SS * HDIM;
    const unsigned short* Vb  = Vt + (size_t)bh * HDIM * SS;
    const unsigned short* Mbb = Mb + (size_t)b_ * TT * TT;
    const int myrow = (w * 16 + col16) * PT;   // this lane's t-row in LDS tiles

    for (int it16 = 0; it16 < 16; ++it16) {
        const int t2b = it16 * 64;
        __syncthreads();  // (A) prev iteration's PV reads done
#pragma unroll
        for (int st = 0; st < 2; ++st) {
            int idx = tid + st * 256;
            int r = idx >> 3, c = (idx & 7) * 8;
            *(uint4*)(K0 + r * PT + c) = *(const uint4*)(Kb + (size_t)(t2b + r) * HDIM + c);
            *(uint4*)(K1 + r * PT + c) = *(const uint4*)(Kb + (size_t)(1024 + t2b + r) * HDIM + c);
            *(uint4*)(V0 + r * PT + c) = *(const uint4*)(Vb + (size_t)r * SS + t2b + c);
            *(uint4*)(V1 + r * PT + c) = *(const uint4*)(Vb + (size_t)r * SS + 1024 + t2b + c);
            *(uint4*)(Ms + r * PT + c) = *(const uint4*)(Mbb + (size_t)(t0 + r) * TT + t2b + c);
        }
        __syncthreads();  // (B)

        // S^T halves: A=K (m=s), B=Q (n=t). sacc[half][js][r]: s=js*16+quad*4+r
        f4v s0acc[4], s1acc[4];
#pragma unroll
        for (int js = 0; js < 4; ++js) { s0acc[js] = (f4v)0.0f; s1acc[js] = (f4v)0.0f; }
#pragma unroll
        for (int ks = 0; ks < 2; ++ks) {
            s8v bq_ = *(const s8v*)(Qs + myrow + ks * 32 + quad * 8);
#pragma unroll
            for (int js = 0; js < 4; ++js) {
                s8v ak0 = *(const s8v*)(K0 + (js * 16 + col16) * PT + ks * 32 + quad * 8);
                s8v ak1 = *(const s8v*)(K1 + (js * 16 + col16) * PT + ks * 32 + quad * 8);
                s0acc[js] = __builtin_amdgcn_mfma_f32_16x16x32_bf16(ak0, bq_, s0acc[js], 0, 0, 0);
                s1acc[js] = __builtin_amdgcn_mfma_f32_16x16x32_bf16(ak1, bq_, s1acc[js], 0, 0, 0);
            }
        }

        // mask add from LDS (bf16): lane's t-row, t2 = js*16+quad*4+r; one b64/js
#pragma unroll
        for (int js = 0; js < 4; ++js) {
            uint2 mm = *(const uint2*)(Ms + myrow + js * 16 + quad * 4);
            float m0f = bf2f((unsigned short)(mm.x & 0xffff));
            float m1f = bf2f((unsigned short)(mm.x >> 16));
            float m2f = bf2f((unsigned short)(mm.y & 0xffff));
            float m3f = bf2f((unsigned short)(mm.y >> 16));
            s0acc[js][0] += m0f; s1acc[js][0] += m0f;
            s0acc[js][1] += m1f; s1acc[js][1] += m1f;
            s0acc[js][2] += m2f; s1acc[js][2] += m2f;
            s0acc[js][3] += m3f; s1acc[js][3] += m3f;
        }

        // online softmax over 32 values (both halves) for this lane's t
        float tmax = -INFINITY;
#pragma unroll
        for (int js = 0; js < 4; ++js)
#pragma unroll
            for (int r = 0; r < 4; ++r)
                tmax = fmaxf(tmax, fmaxf(s0acc[js][r], s1acc[js][r]));
        tmax = fmaxf(tmax, __shfl_xor(tmax, 16));
        tmax = fmaxf(tmax, __shfl_xor(tmax, 32));
        const float mnew = fmaxf(mrun, tmax);
        const float scl = __expf(mrun - mnew);   // 0 on first tile
        float rs = 0.0f;
#pragma unroll
        for (int js = 0; js < 4; ++js)
#pragma unroll
            for (int r = 0; r < 4; ++r) {
                float p0 = __expf(s0acc[js][r] - mnew);
                float p1 = __expf(s1acc[js][r] - mnew);
                s0acc[js][r] = p0; s1acc[js][r] = p1;
                rs += p0 + p1;
            }
        rs += __shfl_xor(rs, 16);
        rs += __shfl_xor(rs, 32);
        lrun = lrun * scl + rs;
        mrun = mnew;

        // rescale O: oacc row t_local = quad*4+r; scl lives at lane col16=t_local
        float sclr[4];
#pragma unroll
        for (int r = 0; r < 4; ++r) sclr[r] = __shfl(scl, quad * 4 + r);
#pragma unroll
        for (int jd = 0; jd < 4; ++jd)
#pragma unroll
            for (int r = 0; r < 4; ++r) oacc[jd][r] *= sclr[r];

        __syncthreads();  // (C) all waves done reading K0/K1

        // store P halves [t][s_local] bf16 into K0/K1 (4 consecutive s per b64)
#pragma unroll
        for (int js = 0; js < 4; ++js) {
            unsigned p01 = (unsigned)f2bf(s0acc[js][0]) | ((unsigned)f2bf(s0acc[js][1]) << 16);
            unsigned p23 = (unsigned)f2bf(s0acc[js][2]) | ((unsigned)f2bf(s0acc[js][3]) << 16);
            *(uint2*)(K0 + myrow + js * 16 + quad * 4) = make_uint2(p01, p23);
            p01 = (unsigned)f2bf(s1acc[js][0]) | ((unsigned)f2bf(s1acc[js][1]) << 16);
            p23 = (unsigned)f2bf(s1acc[js][2]) | ((unsigned)f2bf(s1acc[js][3]) << 16);
            *(uint2*)(K1 + myrow + js * 16 + quad * 4) = make_uint2(p01, p23);
        }
        __syncthreads();  // (D)

        // O += P0.V0 + P1.V1 : A[m=t][k=s] from K0/K1, B[n=d][k=s] from V0/V1
#pragma unroll
        for (int ks = 0; ks < 2; ++ks) {
            s8v p0 = *(const s8v*)(K0 + myrow + ks * 32 + quad * 8);
            s8v p1 = *(const s8v*)(K1 + myrow + ks * 32 + quad * 8);
#pragma unroll
            for (int jd = 0; jd < 4; ++jd) {
                s8v v0_ = *(const s8v*)(V0 + (jd * 16 + col16) * PT + ks * 32 + quad * 8);
                s8v v1_ = *(const s8v*)(V1 + (jd * 16 + col16) * PT + ks * 32 + quad * 8);
                oacc[jd] = __builtin_amdgcn_mfma_f32_16x16x32_bf16(p0, v0_, oacc[jd], 0, 0, 0);
                oacc[jd] = __builtin_amdgcn_mfma_f32_16x16x32_bf16(p1, v1_, oacc[jd], 0, 0, 0);
            }
        }
    }

    // epilogue: normalize (gather 1/l for row t_local=quad*4+r) and write bf16
    const float inv = 1.0f / lrun;
    float invr[4];
#pragma unroll
    for (int r = 0; r < 4; ++r) invr[r] = __shfl(inv, quad * 4 + r);
#pragma unroll
    for (int r = 0; r < 4; ++r) {
        const int t = t0 + w * 16 + quad * 4 + r;
#pragma unroll
        for (int jd = 0; jd < 4; ++jd)
            O[(size_t)(b_ * TT + t) * EE + h * HDIM + jd * 16 + col16] =
                f2bf(oacc[jd][r] * invr[r]);
    }
}

// ---------------------------------------------------------------------------
extern "C" void kernel_launch(void* const* d_in, const int* in_sizes, int n_in,
                              void* d_out, int out_size, void* d_ws, size_t ws_size,
                              hipStream_t stream)
{
    (void)in_sizes; (void)n_in; (void)out_size; (void)ws_size;

    const float* x    = (const float*)d_in[0];
    const float* mask = (const float*)d_in[1];
    const float* Wq   = (const float*)d_in[2];
    const float* bq   = (const float*)d_in[3];
    const float* Wk   = (const float*)d_in[4];
    const float* bk   = (const float*)d_in[5];
    const float* Wv   = (const float*)d_in[6];
    const float* bv   = (const float*)d_in[7];
    const float* Wo   = (const float*)d_in[8];
    const float* bo   = (const float*)d_in[9];
    float* out = (float*)d_out;

    // workspace carve (ushort units): 42M ushorts = 84 MB
    unsigned short* xb  = (unsigned short*)d_ws;
    unsigned short* wqb = xb  + (size_t)MROWS * EE;          // 4M
    unsigned short* wkb = wqb + (size_t)EE * EE;             // 1M
    unsigned short* wvb = wkb + (size_t)2 * EE * EE;         // 2M
    unsigned short* wob = wvb + (size_t)2 * EE * EE;         // 2M
    unsigned short* mb  = wob + (size_t)EE * EE;             // 1M
    unsigned short* qp  = mb  + (size_t)BB * TT * TT;        // 4M
    unsigned short* kp  = qp  + (size_t)MROWS * EE;          // 4M
    unsigned short* vt  = kp  + (size_t)BB * HH * SS * HDIM; // 8M
    unsigned short* ao  = vt  + (size_t)BB * HH * SS * HDIM; // 8M

    dim3 blk(256);

    // fused fp32->bf16 conversion (x + 4 weights + mask)
    cvt6_kernel<<<4096, blk, 0, stream>>>(x, Wq, Wk, Wv, Wo, mask,
                                          xb, wqb, wkb, wvb, wob, mb);
    // fused Q+K projection
    gemm_qk_kernel<<<dim3(32, 24), blk, 0, stream>>>(xb, wqb, wkb, bq, bk, qp, kp);
    // V projection computed transposed (A=Wv, W=x) -> V^T [B,H,HD,S]
    gemm_mfma_kernel<2, 0, EE, MROWS><<<dim3(16, 32), blk, 0, stream>>>(
        wvb, xb, bv, vt, 1.0f);
    // attention (MULT-paired s-tiles, bf16 mask, XCD swizzle)
    attn_mfma2_kernel<<<dim3(1024), blk, 0, stream>>>(qp, kp, vt, mb, ao);
    // output projection -> fp32 out
    gemm_mfma_kernel<0, 1, EE, EE><<<dim3(32, 8), blk, 0, stream>>>(
        ao, wob, bo, out, 1.0f);
}